// Round 4
// baseline (35.263 us; speedup 1.0000x reference)
//
#include <hip/hip_runtime.h>

// Compute the 12 constants of the inverse rigid transform for batch b:
//   R = quat_to_rot(normalize(q));  Rinv = R^T;  tinv = -R^T * t
__device__ __forceinline__ void inv_rigid(const float* __restrict__ dq,
                                          const float* __restrict__ dt,
                                          int b,
                                          float& i00, float& i01, float& i02,
                                          float& i10, float& i11, float& i12,
                                          float& i20, float& i21, float& i22,
                                          float& tix, float& tiy, float& tiz) {
    float qw = dq[b * 4 + 0];
    float qx = dq[b * 4 + 1];
    float qy = dq[b * 4 + 2];
    float qz = dq[b * 4 + 3];
    float inv = 1.0f / sqrtf(qw * qw + qx * qx + qy * qy + qz * qz);
    qw *= inv; qx *= inv; qy *= inv; qz *= inv;

    float r00 = 1.0f - 2.0f * (qy * qy + qz * qz);
    float r01 = 2.0f * (qx * qy - qw * qz);
    float r02 = 2.0f * (qx * qz + qw * qy);
    float r10 = 2.0f * (qx * qy + qw * qz);
    float r11 = 1.0f - 2.0f * (qx * qx + qz * qz);
    float r12 = 2.0f * (qy * qz - qw * qx);
    float r20 = 2.0f * (qx * qz - qw * qy);
    float r21 = 2.0f * (qy * qz + qw * qx);
    float r22 = 1.0f - 2.0f * (qx * qx + qy * qy);

    // Rinv = R^T
    i00 = r00; i01 = r10; i02 = r20;
    i10 = r01; i11 = r11; i12 = r21;
    i20 = r02; i21 = r12; i22 = r22;

    float tx = dt[b * 3 + 0];
    float ty = dt[b * 3 + 1];
    float tz = dt[b * 3 + 2];
    tix = -(i00 * tx + i01 * ty + i02 * tz);
    tiy = -(i10 * tx + i11 * ty + i12 * tz);
    tiz = -(i20 * tx + i21 * ty + i22 * tz);
}

#define ITERS 6

// Per-wave chunk processing. FULL=true -> no per-lane bounds checks (all but
// the last x-block). Each wave owns ITERS contiguous slots of 64 float4s.
//
// Output float4 m covers global floats 4m..4m+3; with r = m%3:
//   r==0: p0=(v.x,v.y,v.z), p1=(v.w, in[m+1].x, in[m+1].y)
//   r==1: p1=(in[m-1].w, v.x, v.y), p2=(v.z, v.w, in[m+1].x)
//   r==2: p2=(in[m-1].z, in[m-1].w, v.x), p3=(v.y,v.z,v.w)
// When N%4==0 the last float4 of each batch has r==2, so the m+1 patch never
// reads past the batch, and m==0 has r==0 so m-1 is never read.
template <bool FULL>
__device__ __forceinline__ void do_chunk(const float4* __restrict__ pin,
                                         float4* __restrict__ pout,
                                         long long base, int wbase,
                                         int m4_per_batch, int lane,
                                         float i00, float i01, float i02,
                                         float i10, float i11, float i12,
                                         float i20, float i21, float i22,
                                         float tix, float tiy, float tiz) {
    float4 v[ITERS];
#pragma unroll
    for (int j = 0; j < ITERS; ++j) {
        int m = wbase + 64 * j;
        if (FULL || m < m4_per_batch)
            v[j] = pin[base + m];
        else
            v[j] = make_float4(0.f, 0.f, 0.f, 0.f);
    }

    // outermost-edge patches, issued early (L1/L2 hits, 1 lane each)
    float2 plo = make_float2(0.f, 0.f), phi = make_float2(0.f, 0.f);
    {
        int m0 = wbase;
        if (lane == 0 && (FULL || m0 < m4_per_batch) && (m0 % 3) != 0)
            plo = *(const float2*)((const float*)(pin + base + m0) - 2);
        int mh = wbase + 64 * (ITERS - 1);
        if (lane == 63 && (FULL || mh < m4_per_batch) && (mh % 3) != 2)
            phi = *(const float2*)(pin + base + mh + 1);
    }

#pragma unroll
    for (int j = 0; j < ITERS; ++j) {
        int m = wbase + 64 * j;
        int r = m % 3;

        // neighbor components within the slot (ds ops)
        float sz = __shfl_up(v[j].z, 1);   // in[m-1].z
        float sw = __shfl_up(v[j].w, 1);   // in[m-1].w
        float sx = __shfl_down(v[j].x, 1); // in[m+1].x
        float sy = __shfl_down(v[j].y, 1); // in[m+1].y

        // slot-boundary patches from adjacent slot registers (readlane bcast)
        if (j > 0) {
            float pz = __shfl(v[j - 1].z, 63);
            float pw = __shfl(v[j - 1].w, 63);
            if (lane == 0) { sz = pz; sw = pw; }
        } else {
            if (lane == 0) { sz = plo.x; sw = plo.y; }
        }
        if (j < ITERS - 1) {
            float nx = __shfl(v[j + 1].x, 0);
            float ny = __shfl(v[j + 1].y, 0);
            if (lane == 63) { sx = nx; sy = ny; }
        } else {
            if (lane == 63) { sx = phi.x; sy = phi.y; }
        }

        float4 o;
        if (r == 0) {
            o.x = i00 * v[j].x + i01 * v[j].y + i02 * v[j].z + tix;
            o.y = i10 * v[j].x + i11 * v[j].y + i12 * v[j].z + tiy;
            o.z = i20 * v[j].x + i21 * v[j].y + i22 * v[j].z + tiz;
            o.w = i00 * v[j].w + i01 * sx     + i02 * sy     + tix;
        } else if (r == 1) {
            o.x = i10 * sw     + i11 * v[j].x + i12 * v[j].y + tiy;
            o.y = i20 * sw     + i21 * v[j].x + i22 * v[j].y + tiz;
            o.z = i00 * v[j].z + i01 * v[j].w + i02 * sx     + tix;
            o.w = i10 * v[j].z + i11 * v[j].w + i12 * sx     + tiy;
        } else {
            o.x = i20 * sz     + i21 * sw     + i22 * v[j].x + tiz;
            o.y = i00 * v[j].y + i01 * v[j].z + i02 * v[j].w + tix;
            o.z = i10 * v[j].y + i11 * v[j].z + i12 * v[j].w + tiy;
            o.w = i20 * v[j].y + i21 * v[j].z + i22 * v[j].w + tiz;
        }

        if (FULL || m < m4_per_batch)
            pout[base + m] = o;   // plain cached store: let L2 combine/stream
    }
}

__global__ void realign_kernel(const float4* __restrict__ pin,
                               float4* __restrict__ pout,
                               const float* __restrict__ T_mis,
                               const float* __restrict__ dq,
                               const float* __restrict__ dt,
                               float* __restrict__ out_T,
                               int m4_per_batch)  // = N*3/4 float4s per batch
{
    int b = blockIdx.y;

    float i00, i01, i02, i10, i11, i12, i20, i21, i22, tix, tiy, tiz;
    inv_rigid(dq, dt, b, i00, i01, i02, i10, i11, i12, i20, i21, i22, tix, tiy, tiz);

    // Fused tiny batch_T_pred = delta_T_inv @ T_mis (16 floats per batch)
    if (blockIdx.x == 0 && threadIdx.x < 16) {
        int i = threadIdx.x >> 2, k = threadIdx.x & 3;
        const float* T = T_mis + b * 16;
        float val;
        if (i == 0)      val = i00 * T[k] + i01 * T[4 + k] + i02 * T[8 + k] + tix * T[12 + k];
        else if (i == 1) val = i10 * T[k] + i11 * T[4 + k] + i12 * T[8 + k] + tiy * T[12 + k];
        else if (i == 2) val = i20 * T[k] + i21 * T[4 + k] + i22 * T[8 + k] + tiz * T[12 + k];
        else             val = T[12 + k];
        out_T[b * 16 + threadIdx.x] = val;
    }

    int lane = threadIdx.x & 63;
    int wave = threadIdx.x >> 6;
    int wbase = blockIdx.x * (blockDim.x * ITERS) + wave * (64 * ITERS) + lane;
    long long base = (long long)b * m4_per_batch;

    // uniform branch: all but the last x-block are full
    bool full = (long long)(blockIdx.x + 1) * (blockDim.x * ITERS) <= m4_per_batch;
    if (full)
        do_chunk<true>(pin, pout, base, wbase, m4_per_batch, lane,
                       i00, i01, i02, i10, i11, i12, i20, i21, i22, tix, tiy, tiz);
    else
        do_chunk<false>(pin, pout, base, wbase, m4_per_batch, lane,
                        i00, i01, i02, i10, i11, i12, i20, i21, i22, tix, tiy, tiz);
}

// Scalar fallback (only used if N*3 % 4 != 0 — not the case here).
__global__ void realign_scalar_kernel(const float* __restrict__ pin,
                                      float* __restrict__ pout,
                                      const float* __restrict__ dq,
                                      const float* __restrict__ dt,
                                      long long n_per_batch) {
    int b = blockIdx.y;
    float i00, i01, i02, i10, i11, i12, i20, i21, i22, tix, tiy, tiz;
    inv_rigid(dq, dt, b, i00, i01, i02, i10, i11, i12, i20, i21, i22, tix, tiy, tiz);
    long long base = (long long)b * n_per_batch * 3LL;
    for (long long p = (long long)blockIdx.x * blockDim.x + threadIdx.x;
         p < n_per_batch; p += (long long)gridDim.x * blockDim.x) {
        float x = pin[base + p * 3 + 0];
        float y = pin[base + p * 3 + 1];
        float z = pin[base + p * 3 + 2];
        pout[base + p * 3 + 0] = i00 * x + i01 * y + i02 * z + tix;
        pout[base + p * 3 + 1] = i10 * x + i11 * y + i12 * z + tiy;
        pout[base + p * 3 + 2] = i20 * x + i21 * y + i22 * z + tiz;
    }
}

__global__ void batch_T_kernel(const float* __restrict__ T_mis,
                               const float* __restrict__ dq,
                               const float* __restrict__ dt,
                               float* __restrict__ out_T, int B) {
    int b = threadIdx.x;
    if (b >= B) return;
    float i00, i01, i02, i10, i11, i12, i20, i21, i22, tix, tiy, tiz;
    inv_rigid(dq, dt, b, i00, i01, i02, i10, i11, i12, i20, i21, i22, tix, tiy, tiz);
    const float* T = T_mis + b * 16;
    float* O = out_T + b * 16;
    float Ri[3][3] = {{i00, i01, i02}, {i10, i11, i12}, {i20, i21, i22}};
    float ti[3] = {tix, tiy, tiz};
#pragma unroll
    for (int i = 0; i < 3; ++i)
#pragma unroll
        for (int k = 0; k < 4; ++k)
            O[i * 4 + k] = Ri[i][0] * T[k] + Ri[i][1] * T[4 + k] +
                           Ri[i][2] * T[8 + k] + ti[i] * T[12 + k];
#pragma unroll
    for (int k = 0; k < 4; ++k) O[12 + k] = T[12 + k];
}

extern "C" void kernel_launch(void* const* d_in, const int* in_sizes, int n_in,
                              void* d_out, int out_size, void* d_ws, size_t ws_size,
                              hipStream_t stream) {
    const float* pcd = (const float*)d_in[0];      // (B, N, 3)
    const float* T_mis = (const float*)d_in[1];    // (B, 4, 4)
    const float* dq = (const float*)d_in[2];       // (B, 4)
    const float* dt = (const float*)d_in[3];       // (B, 3)

    int B = in_sizes[2] / 4;                           // 16
    long long N = (long long)in_sizes[0] / (3LL * B);  // 500000
    long long nf = N * 3LL;                            // floats per batch

    float* out_T = (float*)d_out;                       // first B*16 floats
    float* out_pcd = (float*)d_out + (long long)B * 16; // then B*N*3 floats

    if ((nf & 3LL) == 0LL) {
        int m4 = (int)(nf >> 2);                       // float4s per batch
        int per_block = 256 * ITERS;
        int blocks_x = (m4 + per_block - 1) / per_block;
        dim3 grid(blocks_x, B);
        realign_kernel<<<grid, dim3(256), 0, stream>>>(
            (const float4*)pcd, (float4*)out_pcd, T_mis, dq, dt, out_T, m4);
    } else {
        batch_T_kernel<<<dim3(1), dim3(64), 0, stream>>>(T_mis, dq, dt, out_T, B);
        int blocks_x = (int)((N + 255) / 256);
        if (blocks_x > 4096) blocks_x = 4096;
        dim3 grid(blocks_x, B);
        realign_scalar_kernel<<<grid, dim3(256), 0, stream>>>(
            pcd, out_pcd, dq, dt, N);
    }
}

// Round 5
// 34.714 us; speedup vs baseline: 1.0158x; 1.0158x over previous
//
#include <hip/hip_runtime.h>

// Compute the 12 constants of the inverse rigid transform for batch b:
//   R = quat_to_rot(normalize(q));  Rinv = R^T;  tinv = -R^T * t
__device__ __forceinline__ void inv_rigid(const float* __restrict__ dq,
                                          const float* __restrict__ dt,
                                          int b,
                                          float& i00, float& i01, float& i02,
                                          float& i10, float& i11, float& i12,
                                          float& i20, float& i21, float& i22,
                                          float& tix, float& tiy, float& tiz) {
    float qw = dq[b * 4 + 0];
    float qx = dq[b * 4 + 1];
    float qy = dq[b * 4 + 2];
    float qz = dq[b * 4 + 3];
    float inv = 1.0f / sqrtf(qw * qw + qx * qx + qy * qy + qz * qz);
    qw *= inv; qx *= inv; qy *= inv; qz *= inv;

    float r00 = 1.0f - 2.0f * (qy * qy + qz * qz);
    float r01 = 2.0f * (qx * qy - qw * qz);
    float r02 = 2.0f * (qx * qz + qw * qy);
    float r10 = 2.0f * (qx * qy + qw * qz);
    float r11 = 1.0f - 2.0f * (qx * qx + qz * qz);
    float r12 = 2.0f * (qy * qz - qw * qx);
    float r20 = 2.0f * (qx * qz - qw * qy);
    float r21 = 2.0f * (qy * qz + qw * qx);
    float r22 = 1.0f - 2.0f * (qx * qx + qy * qy);

    // Rinv = R^T
    i00 = r00; i01 = r10; i02 = r20;
    i10 = r01; i11 = r11; i12 = r21;
    i20 = r02; i21 = r12; i22 = r22;

    float tx = dt[b * 3 + 0];
    float ty = dt[b * 3 + 1];
    float tz = dt[b * 3 + 2];
    tix = -(i00 * tx + i01 * ty + i02 * tz);
    tiy = -(i10 * tx + i11 * ty + i12 * tz);
    tiz = -(i20 * tx + i21 * ty + i22 * tz);
}

#define ITERS 4

// Shuffle-free variant: each thread computing output float4 m needs input
// floats 4m-2 .. 4m+5. It loads float4 m plus two predicated float2 edge
// loads (overlapping neighbor lanes' float4s -> L1/L2 hits, no extra HBM).
//
// With r = m%3:
//   r==0: outputs = Row0,1,2 . pt(w2..w4) ; Row0 . pt(w5..w7)  (no low edge)
//   r==1: uses w1 (lo.y) and w4..w6 incl hi.x
//   r==2: uses w0,w1 (lo) only                                  (no high edge)
// where w0,w1 = lo (floats 4m-2,4m-1), w2..w5 = v, w6,w7 = hi (4m+4,4m+5).
// Batch edges: first float4 of a batch has r==0 (skips lo), last has r==2
// (skips hi) since m4_per_batch % 3 == 0 -> no out-of-range reads.
template <bool FULL>
__device__ __forceinline__ void do_chunk(const float4* __restrict__ pin,
                                         float4* __restrict__ pout,
                                         long long base, int wbase,
                                         int m4_per_batch,
                                         float i00, float i01, float i02,
                                         float i10, float i11, float i12,
                                         float i20, float i21, float i22,
                                         float tix, float tiy, float tiz) {
    const float2* __restrict__ p2 = (const float2*)(pin + base);

    float4 v[ITERS];
    float2 lo[ITERS], hi[ITERS];
#pragma unroll
    for (int j = 0; j < ITERS; ++j) {
        int m = wbase + 64 * j;
        int r = m % 3;
        bool a = FULL || (m < m4_per_batch);
        v[j]  = a ? pin[base + m] : make_float4(0.f, 0.f, 0.f, 0.f);
        lo[j] = (a && r != 0) ? p2[2 * m - 1] : make_float2(0.f, 0.f);
        hi[j] = (a && r != 2) ? p2[2 * m + 2] : make_float2(0.f, 0.f);
    }

#pragma unroll
    for (int j = 0; j < ITERS; ++j) {
        int m = wbase + 64 * j;
        int r = m % 3;

        float sz = lo[j].x;  // in float 4m-2
        float sw = lo[j].y;  // in float 4m-1
        float sx = hi[j].x;  // in float 4m+4
        float sy = hi[j].y;  // in float 4m+5

        float4 o;
        if (r == 0) {
            o.x = i00 * v[j].x + i01 * v[j].y + i02 * v[j].z + tix;
            o.y = i10 * v[j].x + i11 * v[j].y + i12 * v[j].z + tiy;
            o.z = i20 * v[j].x + i21 * v[j].y + i22 * v[j].z + tiz;
            o.w = i00 * v[j].w + i01 * sx     + i02 * sy     + tix;
        } else if (r == 1) {
            o.x = i10 * sw     + i11 * v[j].x + i12 * v[j].y + tiy;
            o.y = i20 * sw     + i21 * v[j].x + i22 * v[j].y + tiz;
            o.z = i00 * v[j].z + i01 * v[j].w + i02 * sx     + tix;
            o.w = i10 * v[j].z + i11 * v[j].w + i12 * sx     + tiy;
        } else {
            o.x = i20 * sz     + i21 * sw     + i22 * v[j].x + tiz;
            o.y = i00 * v[j].y + i01 * v[j].z + i02 * v[j].w + tix;
            o.z = i10 * v[j].y + i11 * v[j].z + i12 * v[j].w + tiy;
            o.w = i20 * v[j].y + i21 * v[j].z + i22 * v[j].w + tiz;
        }

        if (FULL || m < m4_per_batch)
            pout[base + m] = o;
    }
}

__global__ void realign_kernel(const float4* __restrict__ pin,
                               float4* __restrict__ pout,
                               const float* __restrict__ T_mis,
                               const float* __restrict__ dq,
                               const float* __restrict__ dt,
                               float* __restrict__ out_T,
                               int m4_per_batch)  // = N*3/4 float4s per batch
{
    int b = blockIdx.y;

    float i00, i01, i02, i10, i11, i12, i20, i21, i22, tix, tiy, tiz;
    inv_rigid(dq, dt, b, i00, i01, i02, i10, i11, i12, i20, i21, i22, tix, tiy, tiz);

    // Fused tiny batch_T_pred = delta_T_inv @ T_mis (16 floats per batch)
    if (blockIdx.x == 0 && threadIdx.x < 16) {
        int i = threadIdx.x >> 2, k = threadIdx.x & 3;
        const float* T = T_mis + b * 16;
        float val;
        if (i == 0)      val = i00 * T[k] + i01 * T[4 + k] + i02 * T[8 + k] + tix * T[12 + k];
        else if (i == 1) val = i10 * T[k] + i11 * T[4 + k] + i12 * T[8 + k] + tiy * T[12 + k];
        else if (i == 2) val = i20 * T[k] + i21 * T[4 + k] + i22 * T[8 + k] + tiz * T[12 + k];
        else             val = T[12 + k];
        out_T[b * 16 + threadIdx.x] = val;
    }

    int lane = threadIdx.x & 63;
    int wave = threadIdx.x >> 6;
    int wbase = blockIdx.x * (blockDim.x * ITERS) + wave * (64 * ITERS) + lane;
    long long base = (long long)b * m4_per_batch;

    // uniform branch: all but the last x-block are full
    bool full = (long long)(blockIdx.x + 1) * (blockDim.x * ITERS) <= m4_per_batch;
    if (full)
        do_chunk<true>(pin, pout, base, wbase, m4_per_batch,
                       i00, i01, i02, i10, i11, i12, i20, i21, i22, tix, tiy, tiz);
    else
        do_chunk<false>(pin, pout, base, wbase, m4_per_batch,
                        i00, i01, i02, i10, i11, i12, i20, i21, i22, tix, tiy, tiz);
}

// Scalar fallback (only used if N*3 % 4 != 0 — not the case here).
__global__ void realign_scalar_kernel(const float* __restrict__ pin,
                                      float* __restrict__ pout,
                                      const float* __restrict__ dq,
                                      const float* __restrict__ dt,
                                      long long n_per_batch) {
    int b = blockIdx.y;
    float i00, i01, i02, i10, i11, i12, i20, i21, i22, tix, tiy, tiz;
    inv_rigid(dq, dt, b, i00, i01, i02, i10, i11, i12, i20, i21, i22, tix, tiy, tiz);
    long long base = (long long)b * n_per_batch * 3LL;
    for (long long p = (long long)blockIdx.x * blockDim.x + threadIdx.x;
         p < n_per_batch; p += (long long)gridDim.x * blockDim.x) {
        float x = pin[base + p * 3 + 0];
        float y = pin[base + p * 3 + 1];
        float z = pin[base + p * 3 + 2];
        pout[base + p * 3 + 0] = i00 * x + i01 * y + i02 * z + tix;
        pout[base + p * 3 + 1] = i10 * x + i11 * y + i12 * z + tiy;
        pout[base + p * 3 + 2] = i20 * x + i21 * y + i22 * z + tiz;
    }
}

__global__ void batch_T_kernel(const float* __restrict__ T_mis,
                               const float* __restrict__ dq,
                               const float* __restrict__ dt,
                               float* __restrict__ out_T, int B) {
    int b = threadIdx.x;
    if (b >= B) return;
    float i00, i01, i02, i10, i11, i12, i20, i21, i22, tix, tiy, tiz;
    inv_rigid(dq, dt, b, i00, i01, i02, i10, i11, i12, i20, i21, i22, tix, tiy, tiz);
    const float* T = T_mis + b * 16;
    float* O = out_T + b * 16;
    float Ri[3][3] = {{i00, i01, i02}, {i10, i11, i12}, {i20, i21, i22}};
    float ti[3] = {tix, tiy, tiz};
#pragma unroll
    for (int i = 0; i < 3; ++i)
#pragma unroll
        for (int k = 0; k < 4; ++k)
            O[i * 4 + k] = Ri[i][0] * T[k] + Ri[i][1] * T[4 + k] +
                           Ri[i][2] * T[8 + k] + ti[i] * T[12 + k];
#pragma unroll
    for (int k = 0; k < 4; ++k) O[12 + k] = T[12 + k];
}

extern "C" void kernel_launch(void* const* d_in, const int* in_sizes, int n_in,
                              void* d_out, int out_size, void* d_ws, size_t ws_size,
                              hipStream_t stream) {
    const float* pcd = (const float*)d_in[0];      // (B, N, 3)
    const float* T_mis = (const float*)d_in[1];    // (B, 4, 4)
    const float* dq = (const float*)d_in[2];       // (B, 4)
    const float* dt = (const float*)d_in[3];       // (B, 3)

    int B = in_sizes[2] / 4;                           // 16
    long long N = (long long)in_sizes[0] / (3LL * B);  // 500000
    long long nf = N * 3LL;                            // floats per batch

    float* out_T = (float*)d_out;                       // first B*16 floats
    float* out_pcd = (float*)d_out + (long long)B * 16; // then B*N*3 floats

    // float4 fast path requires nf % 4 == 0 (so last float4 has r==2) and
    // m4 % 3 == 0 for the edge-skip invariants; nf = N*3 -> m4 = N*3/4,
    // m4 % 3 == 0 iff N % 4 == 0. Both hold for N=500000.
    if ((nf & 3LL) == 0LL && ((nf >> 2) % 3LL) == 0LL) {
        int m4 = (int)(nf >> 2);                       // float4s per batch
        int per_block = 256 * ITERS;
        int blocks_x = (m4 + per_block - 1) / per_block;
        dim3 grid(blocks_x, B);
        realign_kernel<<<grid, dim3(256), 0, stream>>>(
            (const float4*)pcd, (float4*)out_pcd, T_mis, dq, dt, out_T, m4);
    } else {
        batch_T_kernel<<<dim3(1), dim3(64), 0, stream>>>(T_mis, dq, dt, out_T, B);
        int blocks_x = (int)((N + 255) / 256);
        if (blocks_x > 4096) blocks_x = 4096;
        dim3 grid(blocks_x, B);
        realign_scalar_kernel<<<grid, dim3(256), 0, stream>>>(
            pcd, out_pcd, dq, dt, N);
    }
}